// Round 1
// baseline (460.092 us; speedup 1.0000x reference)
//
#include <hip/hip_runtime.h>
#include <math.h>

#define D_DIM 4096
#define E_DIM 64
#define TM 64                 // tokens per block
#define BK 64                 // k-chunk
#define NC (D_DIM / BK)       // 64 chunks
#define TP 68                 // padded token/expert stride in transposed LDS tiles (mult of 4 for float4)
#define LP 65                 // logits pad (2-way bank access in epilogue = free)

__global__ __launch_bounds__(256, 1) void router_kernel(
    const float* __restrict__ hs,
    const float* __restrict__ W,
    const float* __restrict__ bias,
    float* __restrict__ out,
    int nTok)
{
    __shared__ float hsT[BK * TP];   // [k][token]
    __shared__ float wT [BK * TP];   // [k][expert]
    __shared__ float lg [TM * LP];   // [token][expert]
    __shared__ float s_m[TM];
    __shared__ float s_inv[TM];

    const int tid   = threadIdx.x;
    const int tBase = blockIdx.x * TM;

    const int ty = tid >> 4;      // 0..15 token quad
    const int tx = tid & 15;      // 0..15 expert quad

    // loader mapping: lane covers one d within the chunk (coalesced), 4 rows per pass
    const int ld_d = tid & 63;    // 0..63
    const int ld_g = tid >> 6;    // 0..3

    float4 ph[4], pw[4];
    float acc[4][4];
    #pragma unroll
    for (int i = 0; i < 4; ++i)
        #pragma unroll
        for (int j = 0; j < 4; ++j)
            acc[i][j] = 0.f;

    const float* hsB = hs + (size_t)tBase * D_DIM;

    auto g_load = [&](int c) {
        const int d = c * BK + ld_d;
        #pragma unroll
        for (int p = 0; p < 4; ++p) {
            const int t0 = ld_g * 16 + p * 4;
            ph[p].x = hsB[(size_t)(t0 + 0) * D_DIM + d];
            ph[p].y = hsB[(size_t)(t0 + 1) * D_DIM + d];
            ph[p].z = hsB[(size_t)(t0 + 2) * D_DIM + d];
            ph[p].w = hsB[(size_t)(t0 + 3) * D_DIM + d];
            pw[p].x = W[(size_t)(t0 + 0) * D_DIM + d];
            pw[p].y = W[(size_t)(t0 + 1) * D_DIM + d];
            pw[p].z = W[(size_t)(t0 + 2) * D_DIM + d];
            pw[p].w = W[(size_t)(t0 + 3) * D_DIM + d];
        }
    };

    auto l_store = [&]() {
        #pragma unroll
        for (int p = 0; p < 4; ++p) {
            const int t0 = ld_g * 16 + p * 4;
            *(float4*)&hsT[ld_d * TP + t0] = ph[p];   // transposed: [d][token]
            *(float4*)&wT [ld_d * TP + t0] = pw[p];   // transposed: [d][expert]
        }
    };

    auto compute = [&]() {
        #pragma unroll
        for (int kk = 0; kk < BK; ++kk) {
            const float4 a = *(const float4*)&hsT[kk * TP + ty * 4];
            const float4 w = *(const float4*)&wT [kk * TP + tx * 4];
            const float av[4] = {a.x, a.y, a.z, a.w};
            const float wv[4] = {w.x, w.y, w.z, w.w};
            #pragma unroll
            for (int i = 0; i < 4; ++i)
                #pragma unroll
                for (int j = 0; j < 4; ++j)
                    acc[i][j] = fmaf(av[i], wv[j], acc[i][j]);
        }
    };

    // pipeline: regs hold chunk c+1 while LDS serves chunk c
    g_load(0);
    l_store();
    __syncthreads();
    for (int c = 0; c < NC - 1; ++c) {
        g_load(c + 1);
        compute();
        __syncthreads();
        l_store();
        __syncthreads();
    }
    compute();

    // ---- epilogue: logits (+bias) to LDS ----
    #pragma unroll
    for (int i = 0; i < 4; ++i)
        #pragma unroll
        for (int j = 0; j < 4; ++j)
            lg[(ty * 4 + i) * LP + (tx * 4 + j)] = acc[i][j] + bias[tx * 4 + j];
    __syncthreads();

    float* out_idx = out;
    float* out_val = out + (size_t)nTok * 2;
    float* out_sc  = out + (size_t)nTok * 4;

    if (tid < TM) {
        const int t = tid;
        const float* row = &lg[t * LP];
        float m = row[0];
        #pragma unroll
        for (int e = 1; e < E_DIM; ++e) m = fmaxf(m, row[e]);
        float sum = 0.f;
        float b1 = -INFINITY, b2 = -INFINITY;
        int i1 = 0, i2 = 0;
        for (int e = 0; e < E_DIM; ++e) {
            const float l = row[e];
            sum += __expf(l - m);
            // strict > : ties keep the lower index first (matches jax.lax.top_k)
            if (l > b1)      { b2 = b1; i2 = i1; b1 = l; i1 = e; }
            else if (l > b2) { b2 = l; i2 = e; }
        }
        const float inv = 1.f / sum;
        s_m[t]   = m;
        s_inv[t] = inv;
        const size_t gt = (size_t)(tBase + t);
        out_idx[gt * 2 + 0] = (float)i1;     // indices written as float32
        out_idx[gt * 2 + 1] = (float)i2;
        out_val[gt * 2 + 0] = __expf(b1 - m) * inv;
        out_val[gt * 2 + 1] = __expf(b2 - m) * inv;
    }
    __syncthreads();

    // cooperative, coalesced scores write: lanes cover one full token row (256 B)
    const int e  = tid & 63;
    const int tq = tid >> 6;
    #pragma unroll
    for (int p = 0; p < 16; ++p) {
        const int t = p * 4 + tq;
        out_sc[(size_t)(tBase + t) * E_DIM + e] =
            __expf(lg[t * LP + e] - s_m[t]) * s_inv[t];
    }
}

extern "C" void kernel_launch(void* const* d_in, const int* in_sizes, int n_in,
                              void* d_out, int out_size, void* d_ws, size_t ws_size,
                              hipStream_t stream) {
    const float* hs = (const float*)d_in[0];
    const float* W  = (const float*)d_in[1];
    const float* b  = (const float*)d_in[2];
    float* out = (float*)d_out;
    const int nTok = in_sizes[0] / D_DIM;   // 16384
    dim3 grid(nTok / TM), block(256);
    router_kernel<<<grid, block, 0, stream>>>(hs, W, b, out, nTok);
}

// Round 2
// 446.098 us; speedup vs baseline: 1.0314x; 1.0314x over previous
//
#include <hip/hip_runtime.h>
#include <math.h>

#define D_DIM 4096
#define E_DIM 64
#define TM 64                  // tokens per block (gemm)
#define BK 64                  // k-chunk
#define KSPLIT 4               // K-split factor -> grid 1024 = 4 blocks/CU
#define KPART (D_DIM / KSPLIT) // 1024
#define KCH (KPART / BK)       // 16 chunks per part
#define TP 68                  // padded stride in transposed LDS tiles
#define LP 65                  // logits pad in epilogue kernel

// ---------------- kernel 1: K-split GEMM, atomic partial-logit accumulate ----------------
__global__ __launch_bounds__(256, 4) void router_gemm(
    const float* __restrict__ hs,
    const float* __restrict__ W,
    float* __restrict__ logits,   // [nTok, 64], pre-zeroed
    int nTok)
{
    __shared__ float hsT[BK * TP];   // [d][token]
    __shared__ float wT [BK * TP];   // [d][expert]

    const int tid   = threadIdx.x;
    const int part  = blockIdx.x & (KSPLIT - 1);
    const int tBase = (blockIdx.x >> 2) * TM;
    const int kBase = part * KPART;

    const int ty = tid >> 4;      // 0..15 token quad
    const int tx = tid & 15;      // 0..15 expert quad

    // loader mapping: dq fast within wave for coalescing
    const int dq = tid & 15;      // d-quad: covers 64 d's as float4
    const int r  = tid >> 4;      // 0..15 row; pass p adds p*16

    float4 ph[4], pw[4];
    float acc[4][4];
    #pragma unroll
    for (int i = 0; i < 4; ++i)
        #pragma unroll
        for (int j = 0; j < 4; ++j)
            acc[i][j] = 0.f;

    const float* hsB = hs + (size_t)tBase * D_DIM + kBase;
    const float* WB  = W + kBase;

    auto g_load = [&](int c) {
        const int d = c * BK + dq * 4;
        #pragma unroll
        for (int p = 0; p < 4; ++p) {
            const int row = p * 16 + r;
            ph[p] = *(const float4*)&hsB[(size_t)row * D_DIM + d];
            pw[p] = *(const float4*)&WB [(size_t)row * D_DIM + d];
        }
    };

    auto l_store = [&]() {
        #pragma unroll
        for (int p = 0; p < 4; ++p) {
            const int row = p * 16 + r;
            #pragma unroll
            for (int i = 0; i < 4; ++i) {
                hsT[(dq * 4 + i) * TP + row] = ((const float*)&ph[p])[i];
                wT [(dq * 4 + i) * TP + row] = ((const float*)&pw[p])[i];
            }
        }
    };

    auto compute = [&]() {
        #pragma unroll
        for (int kk = 0; kk < BK; ++kk) {
            const float4 a = *(const float4*)&hsT[kk * TP + ty * 4];
            const float4 w = *(const float4*)&wT [kk * TP + tx * 4];
            const float av[4] = {a.x, a.y, a.z, a.w};
            const float wv[4] = {w.x, w.y, w.z, w.w};
            #pragma unroll
            for (int i = 0; i < 4; ++i)
                #pragma unroll
                for (int j = 0; j < 4; ++j)
                    acc[i][j] = fmaf(av[i], wv[j], acc[i][j]);
        }
    };

    g_load(0);
    l_store();
    __syncthreads();
    #pragma unroll 1
    for (int c = 0; c < KCH - 1; ++c) {
        g_load(c + 1);           // issue VMEM early; latency hidden by compute
        compute();
        __syncthreads();
        l_store();
        __syncthreads();
    }
    compute();

    // atomic partial accumulate (bias added in kernel 2)
    #pragma unroll
    for (int i = 0; i < 4; ++i) {
        const size_t rowOff = (size_t)(tBase + ty * 4 + i) * E_DIM + tx * 4;
        #pragma unroll
        for (int j = 0; j < 4; ++j)
            unsafeAtomicAdd(&logits[rowOff + j], acc[i][j]);
    }
}

// ---------------- kernel 2: bias + softmax + top-2, in-place over logits ----------------
__global__ __launch_bounds__(256, 4) void router_epilogue(
    const float* __restrict__ bias,
    float* __restrict__ out,
    int nTok)
{
    __shared__ float lg[64 * LP];
    __shared__ float s_m[64];
    __shared__ float s_inv[64];

    const int tid   = threadIdx.x;
    const int tBase = blockIdx.x * 64;

    float* out_idx = out;
    float* out_val = out + (size_t)nTok * 2;
    float* sc      = out + (size_t)nTok * 4;

    // stage 64x64 logits coalesced, add bias
    #pragma unroll
    for (int p = 0; p < 4; ++p) {
        const int f = p * 1024 + tid * 4;
        const float4 v  = *(const float4*)&sc[(size_t)tBase * E_DIM + f];
        const int t = f >> 6, e = f & 63;
        const float4 bb = *(const float4*)&bias[e];
        lg[t * LP + e + 0] = v.x + bb.x;
        lg[t * LP + e + 1] = v.y + bb.y;
        lg[t * LP + e + 2] = v.z + bb.z;
        lg[t * LP + e + 3] = v.w + bb.w;
    }
    __syncthreads();

    if (tid < 64) {
        const int t = tid;
        const float* row = &lg[t * LP];
        float m = row[0];
        #pragma unroll
        for (int e = 1; e < E_DIM; ++e) m = fmaxf(m, row[e]);
        float sum = 0.f;
        float b1 = -INFINITY, b2 = -INFINITY;
        int i1 = 0, i2 = 0;
        for (int e = 0; e < E_DIM; ++e) {
            const float l = row[e];
            sum += __expf(l - m);
            if (l > b1)      { b2 = b1; i2 = i1; b1 = l; i1 = e; }
            else if (l > b2) { b2 = l; i2 = e; }
        }
        const float inv = 1.f / sum;
        s_m[t]   = m;
        s_inv[t] = inv;
        const size_t gt = (size_t)(tBase + t);
        out_idx[gt * 2 + 0] = (float)i1;
        out_idx[gt * 2 + 1] = (float)i2;
        out_val[gt * 2 + 0] = __expf(b1 - m) * inv;
        out_val[gt * 2 + 1] = __expf(b2 - m) * inv;
    }
    __syncthreads();

    // coalesced scores write (overwrites logits region)
    const int e  = tid & 63;
    const int tq = tid >> 6;
    #pragma unroll
    for (int p = 0; p < 16; ++p) {
        const int t = p * 4 + tq;
        sc[(size_t)(tBase + t) * E_DIM + e] =
            __expf(lg[t * LP + e] - s_m[t]) * s_inv[t];
    }
}

extern "C" void kernel_launch(void* const* d_in, const int* in_sizes, int n_in,
                              void* d_out, int out_size, void* d_ws, size_t ws_size,
                              hipStream_t stream) {
    const float* hs = (const float*)d_in[0];
    const float* W  = (const float*)d_in[1];
    const float* b  = (const float*)d_in[2];
    float* out = (float*)d_out;
    const int nTok = in_sizes[0] / D_DIM;   // 16384

    float* logits = out + (size_t)nTok * 4;  // scores region doubles as logit accumulator
    hipMemsetAsync(logits, 0, (size_t)nTok * E_DIM * sizeof(float), stream);

    dim3 g1(nTok / TM * KSPLIT), b1(256);
    router_gemm<<<g1, b1, 0, stream>>>(hs, W, logits, nTok);

    dim3 g2(nTok / 64), b2(256);
    router_epilogue<<<g2, b2, 0, stream>>>(b, out, nTok);
}

// Round 3
// 385.122 us; speedup vs baseline: 1.1947x; 1.1583x over previous
//
#include <hip/hip_runtime.h>
#include <math.h>

#define D_DIM 4096
#define E_DIM 64
#define TM 64                    // tokens per block
#define KSPLIT 4
#define KPART (D_DIM / KSPLIT)   // 1024
#define CHK 64                   // k per chunk
#define NCH (KPART / CHK)        // 16
#define WROW 72                  // padded k-stride (elements) for W LDS rows

typedef __attribute__((ext_vector_type(8))) short bf16x8;
typedef __attribute__((ext_vector_type(4))) float f32x4;

// error-free 3-level split: f = hi + mid + lo(+2^-24 rel), residuals exact
__device__ inline void split3(const f32x4 a0, const f32x4 a1,
                              bf16x8& fh, bf16x8& fm, bf16x8& fl) {
    uint uh[8], um[8], ul[8];
    float f[8] = {a0[0], a0[1], a0[2], a0[3], a1[0], a1[1], a1[2], a1[3]};
    #pragma unroll
    for (int j = 0; j < 8; ++j) {
        const uint u = __float_as_uint(f[j]);
        const uint h = u & 0xFFFF0000u;               // truncate to bf16
        const float r = f[j] - __uint_as_float(h);    // exact residual
        const uint m = __float_as_uint(r) & 0xFFFF0000u;
        const float r2 = r - __uint_as_float(m);      // exact residual
        uh[j] = h; um[j] = m; ul[j] = __float_as_uint(r2);
    }
    union { bf16x8 v; uint u[4]; } H, M, L;
    #pragma unroll
    for (int j = 0; j < 4; ++j) {
        H.u[j] = (uh[2*j] >> 16) | (uh[2*j+1] & 0xFFFF0000u);
        M.u[j] = (um[2*j] >> 16) | (um[2*j+1] & 0xFFFF0000u);
        L.u[j] = (ul[2*j] >> 16) | (ul[2*j+1] & 0xFFFF0000u);
    }
    fh = H.v; fm = M.v; fl = L.v;
}

// ---------------- kernel 1: K-split MFMA GEMM, atomic partial-logit accumulate ----------------
__global__ __launch_bounds__(256, 4) void router_gemm(
    const float* __restrict__ hs,
    const float* __restrict__ W,
    float* __restrict__ logits,   // [nTok, 64], pre-zeroed
    int nTok)
{
    __shared__ short wsh[E_DIM * WROW];
    __shared__ short wsm[E_DIM * WROW];
    __shared__ short wsl[E_DIM * WROW];

    const int tid  = threadIdx.x;
    const int lane = tid & 63;
    const int wv   = tid >> 6;                  // wave 0..3 -> token group
    const int part = blockIdx.x & (KSPLIT - 1);
    const int tb   = (blockIdx.x >> 2) * TM;
    const int kb   = part * KPART;

    const int l15 = lane & 15;                  // A: token within wave-tile; B: expert within tile
    const int lq  = lane >> 4;                  // k-quad (8 k's)

    // A fragments straight from global: lane holds A[m=l15][k=lq*8+j] (contiguous 32 B)
    const float* aptr = hs + (size_t)(tb + wv * 16 + l15) * D_DIM + kb + lq * 8;
    // W staging: thread covers expert we, 16 consecutive k (2 groups of 8)
    const int we = tid >> 2;
    const int wq = tid & 3;
    const float* wptr = W + (size_t)we * D_DIM + kb + wq * 16;

    f32x4 acc[4];
    #pragma unroll
    for (int t = 0; t < 4; ++t) acc[t] = (f32x4){0.f, 0.f, 0.f, 0.f};

    f32x4 ca[4], pa[4], wr[4];

    auto loadA = [&](int ch, f32x4* dst) {
        const float* p = aptr + ch * CHK;
        dst[0] = *(const f32x4*)(p);
        dst[1] = *(const f32x4*)(p + 4);
        dst[2] = *(const f32x4*)(p + 32);
        dst[3] = *(const f32x4*)(p + 36);
    };
    auto loadW = [&](int ch) {
        const float* p = wptr + ch * CHK;
        wr[0] = *(const f32x4*)(p);
        wr[1] = *(const f32x4*)(p + 4);
        wr[2] = *(const f32x4*)(p + 8);
        wr[3] = *(const f32x4*)(p + 12);
    };
    auto storeW = [&]() {
        bf16x8 h0, m0, l0, h1, m1, l1;
        split3(wr[0], wr[1], h0, m0, l0);
        split3(wr[2], wr[3], h1, m1, l1);
        const int base = we * WROW + wq * 16;
        *(bf16x8*)&wsh[base] = h0;  *(bf16x8*)&wsh[base + 8] = h1;   // ds_write_b128, bank-uniform
        *(bf16x8*)&wsm[base] = m0;  *(bf16x8*)&wsm[base + 8] = m1;
        *(bf16x8*)&wsl[base] = l0;  *(bf16x8*)&wsl[base + 8] = l1;
    };
    auto compute = [&](const f32x4* a) {
        #pragma unroll
        for (int s = 0; s < 2; ++s) {
            bf16x8 ah, am, al;
            split3(a[2 * s], a[2 * s + 1], ah, am, al);
            const int koff = s * 32 + lq * 8;
            #pragma unroll
            for (int t = 0; t < 4; ++t) {
                const int rb = (t * 16 + l15) * WROW + koff;
                const bf16x8 bh = *(const bf16x8*)&wsh[rb];
                const bf16x8 bm = *(const bf16x8*)&wsm[rb];
                const bf16x8 bl = *(const bf16x8*)&wsl[rb];
                acc[t] = __builtin_amdgcn_mfma_f32_16x16x32_bf16(ah, bh, acc[t], 0, 0, 0);
                acc[t] = __builtin_amdgcn_mfma_f32_16x16x32_bf16(ah, bm, acc[t], 0, 0, 0);
                acc[t] = __builtin_amdgcn_mfma_f32_16x16x32_bf16(am, bh, acc[t], 0, 0, 0);
                acc[t] = __builtin_amdgcn_mfma_f32_16x16x32_bf16(ah, bl, acc[t], 0, 0, 0);
                acc[t] = __builtin_amdgcn_mfma_f32_16x16x32_bf16(al, bh, acc[t], 0, 0, 0);
                acc[t] = __builtin_amdgcn_mfma_f32_16x16x32_bf16(am, bm, acc[t], 0, 0, 0);
            }
        }
    };

    loadA(0, ca);
    loadW(0);
    storeW();
    __syncthreads();
    #pragma unroll 1
    for (int ch = 0; ch < NCH; ++ch) {
        const bool last = (ch == NCH - 1);
        if (!last) loadA(ch + 1, pa);       // in flight during compute
        compute(ca);
        if (!last) {
            loadW(ch + 1);                  // L2-resident, short latency
            __syncthreads();                // all waves done reading W LDS
            storeW();
            __syncthreads();                // W chunk ready
            #pragma unroll
            for (int i = 0; i < 4; ++i) ca[i] = pa[i];
        }
    }

    // C/D layout: col(expert) = l15, row(token) = lq*4 + r
    float* dst = logits + (size_t)(tb + wv * 16) * E_DIM;
    #pragma unroll
    for (int t = 0; t < 4; ++t)
        #pragma unroll
        for (int r = 0; r < 4; ++r)
            unsafeAtomicAdd(&dst[(size_t)(lq * 4 + r) * E_DIM + t * 16 + l15], acc[t][r]);
}

// ---------------- kernel 2: bias + softmax + top-2, LDS-free, 4 lanes/token ----------------
__global__ __launch_bounds__(256, 4) void router_epilogue(
    const float* __restrict__ bias,
    float* __restrict__ out,
    int nTok)
{
    const int tid = threadIdx.x;
    const int tok = blockIdx.x * 64 + (tid >> 2);
    const int g   = tid & 3;

    float* out_idx = out;
    float* out_val = out + (size_t)nTok * 2;
    float* sc      = out + (size_t)nTok * 4;

    float* src = sc + (size_t)tok * E_DIM + g * 16;
    float v[16];
    #pragma unroll
    for (int j = 0; j < 4; ++j) {
        const f32x4 x = *(const f32x4*)(src + j * 4);
        const f32x4 b = *(const f32x4*)(bias + g * 16 + j * 4);
        v[j * 4 + 0] = x[0] + b[0];
        v[j * 4 + 1] = x[1] + b[1];
        v[j * 4 + 2] = x[2] + b[2];
        v[j * 4 + 3] = x[3] + b[3];
    }

    // local top-2 (ascending index, strict > keeps lowest index)
    float b1 = -INFINITY, b2 = -INFINITY;
    int i1 = 0, i2 = 0;
    #pragma unroll
    for (int j = 0; j < 16; ++j) {
        const float x = v[j];
        const int idx = g * 16 + j;
        if (x > b1)      { b2 = b1; i2 = i1; b1 = x; i1 = idx; }
        else if (x > b2) { b2 = x; i2 = idx; }
    }
    // butterfly merge across the 4 lanes of this token
    #pragma unroll
    for (int d = 1; d <= 2; d <<= 1) {
        const float ob1 = __shfl_xor(b1, d);
        const int   oi1 = __shfl_xor(i1, d);
        const float ob2 = __shfl_xor(b2, d);
        const int   oi2 = __shfl_xor(i2, d);
        if (ob1 > b1 || (ob1 == b1 && oi1 < i1)) {
            if (b1 > ob2 || (b1 == ob2 && i1 < oi2)) { b2 = b1; i2 = i1; }
            else                                     { b2 = ob2; i2 = oi2; }
            b1 = ob1; i1 = oi1;
        } else {
            if (ob1 > b2 || (ob1 == b2 && oi1 < i2)) { b2 = ob1; i2 = oi1; }
        }
    }
    const float m = b1;   // top-1 value is the row max

    float e[16];
    float s = 0.f;
    #pragma unroll
    for (int j = 0; j < 16; ++j) { e[j] = __expf(v[j] - m); s += e[j]; }
    s += __shfl_xor(s, 1);
    s += __shfl_xor(s, 2);
    const float inv = 1.f / s;

    if (g == 0) {
        out_idx[(size_t)tok * 2 + 0] = (float)i1;
        out_idx[(size_t)tok * 2 + 1] = (float)i2;
        out_val[(size_t)tok * 2 + 0] = inv;                    // exp(b1-m)=1
        out_val[(size_t)tok * 2 + 1] = __expf(b2 - m) * inv;
    }

    #pragma unroll
    for (int j = 0; j < 4; ++j) {
        f32x4 o;
        o[0] = e[j * 4 + 0] * inv;
        o[1] = e[j * 4 + 1] * inv;
        o[2] = e[j * 4 + 2] * inv;
        o[3] = e[j * 4 + 3] * inv;
        *(f32x4*)(src + j * 4) = o;
    }
}

extern "C" void kernel_launch(void* const* d_in, const int* in_sizes, int n_in,
                              void* d_out, int out_size, void* d_ws, size_t ws_size,
                              hipStream_t stream) {
    const float* hs = (const float*)d_in[0];
    const float* W  = (const float*)d_in[1];
    const float* b  = (const float*)d_in[2];
    float* out = (float*)d_out;
    const int nTok = in_sizes[0] / D_DIM;   // 16384

    float* logits = out + (size_t)nTok * 4;  // scores region doubles as logit accumulator
    hipMemsetAsync(logits, 0, (size_t)nTok * E_DIM * sizeof(float), stream);

    dim3 g1(nTok / TM * KSPLIT), b1(256);
    router_gemm<<<g1, b1, 0, stream>>>(hs, W, logits, nTok);

    dim3 g2(nTok / 64), b2(256);
    router_epilogue<<<g2, b2, 0, stream>>>(b, out, nTok);
}